// Round 11
// baseline (287.033 us; speedup 1.0000x reference)
//
#include <hip/hip_runtime.h>

typedef unsigned short u16;
typedef unsigned int u32;
typedef __attribute__((ext_vector_type(4))) float f32x4;
typedef __attribute__((ext_vector_type(8))) short bf16x8;
typedef __attribute__((ext_vector_type(8))) u16 u16x8;
typedef __attribute__((ext_vector_type(4))) u16 u16x4;
typedef __attribute__((ext_vector_type(4))) u32 u32x4;

#define DEVI __device__ __forceinline__

constexpr int C_ = 512, S_ = 32768, L_ = 256, CTX_ = 768;

DEVI u16 f2b(float f) {  // fp32 -> bf16 RNE
    union { float f; unsigned u; } x; x.f = f;
    unsigned r = x.u + 0x7fffu + ((x.u >> 16) & 1u);
    return (u16)(r >> 16);
}

DEVI f32x4 mfma16(bf16x8 a, bf16x8 b, f32x4 c) {
    return __builtin_amdgcn_mfma_f32_16x16x32_bf16(a, b, c, 0, 0, 0);
}

DEVI void gload16(const void* g, void* l) {
    __builtin_amdgcn_global_load_lds(
        (const __attribute__((address_space(1))) void*)g,
        (__attribute__((address_space(3))) void*)l, 16, 0, 0);
}

DEVI u32 cvtpk(float lo, float hi) {  // word = (bf16(hi)<<16) | bf16(lo)
    u32 d;
    asm("v_cvt_pk_bf16_f32 %0, %1, %2" : "=v"(d) : "v"(lo), "v"(hi));
    return d;
}
DEVI void pl32(u32& a, u32& b) {
    asm volatile("v_permlane32_swap_b32 %0, %1" : "+v"(a), "+v"(b));
}
DEVI void pl16(u32& a, u32& b) {
    asm volatile("v_permlane16_swap_b32 %0, %1" : "+v"(a), "+v"(b));
}

// ------------------------------------- weights cvt + LayerNorm(ctx) merged
__global__ __launch_bounds__(256) void prep_small(
    const float* __restrict__ a0, const float* __restrict__ a1,
    const float* __restrict__ a2, const float* __restrict__ a3,
    u16* __restrict__ o0, u16* __restrict__ o1,
    u16* __restrict__ o2, u16* __restrict__ o3,
    const float* __restrict__ ctx, const float* __restrict__ lw,
    const float* __restrict__ lb, u16* __restrict__ cn)
{
    const int which = blockIdx.y, tid = threadIdx.x;
    if (which < 4) {
        const float* src = which == 0 ? a0 : which == 1 ? a1 : which == 2 ? a2 : a3;
        u16* dst = which == 0 ? o0 : which == 1 ? o1 : which == 2 ? o2 : o3;
        int n4 = (which == 1 || which == 2) ? (512 * 768 / 4) : (512 * 512 / 4);
        int i = blockIdx.x * 256 + tid;
        if (i < n4) {
            float4 v = ((const float4*)src)[i];
            u16x4 o; o[0] = f2b(v.x); o[1] = f2b(v.y); o[2] = f2b(v.z); o[3] = f2b(v.w);
            ((u16x4*)dst)[i] = o;
        }
        return;
    }
    // LayerNorm over ctx rows
    const int row = blockIdx.x;
    const float* p = ctx + (size_t)row * CTX_;
    float v0 = p[tid], v1 = p[tid + 256], v2 = p[tid + 512];
    float s1 = v0 + v1 + v2, s2 = v0 * v0 + v1 * v1 + v2 * v2;
    for (int m = 1; m < 64; m <<= 1) { s1 += __shfl_xor(s1, m); s2 += __shfl_xor(s2, m); }
    __shared__ float a1s[4], a2s[4];
    int w = tid >> 6, lane = tid & 63;
    if (lane == 0) { a1s[w] = s1; a2s[w] = s2; }
    __syncthreads();
    s1 = a1s[0] + a1s[1] + a1s[2] + a1s[3];
    s2 = a2s[0] + a2s[1] + a2s[2] + a2s[3];
    const float invN = 1.0f / 768.0f;
    float mu = s1 * invN, rstd = rsqrtf(s2 * invN - mu * mu + 1e-5f);
    u16* o = cn + (size_t)row * CTX_;
    o[tid]       = f2b((v0 - mu) * rstd * lw[tid]       + lb[tid]);
    o[tid + 256] = f2b((v1 - mu) * rstd * lw[tid + 256] + lb[tid + 256]);
    o[tid + 512] = f2b((v2 - mu) * rstd * lw[tid + 512] + lb[tid + 512]);
}

// ---------------------------------------------------------------- GN stats
__global__ __launch_bounds__(256) void gn_partial(const float* __restrict__ x,
                                                  float* __restrict__ part)
{
    const int bg = blockIdx.y, blk = blockIdx.x, tid = threadIdx.x;
    const float* base = x + (size_t)bg * 64 * S_ + (size_t)blk * 1024 + tid * 4;
    float s1 = 0.f, s2 = 0.f;
    for (int c = 0; c < 64; ++c) {
        float4 v = *(const float4*)(base + (size_t)c * S_);
        s1 += v.x + v.y + v.z + v.w;
        s2 += v.x * v.x + v.y * v.y + v.z * v.z + v.w * v.w;
    }
    for (int m = 1; m < 64; m <<= 1) { s1 += __shfl_xor(s1, m); s2 += __shfl_xor(s2, m); }
    __shared__ float a1[4], a2[4];
    int w = tid >> 6, lane = tid & 63;
    if (lane == 0) { a1[w] = s1; a2[w] = s2; }
    __syncthreads();
    if (tid == 0) {
        part[(bg * 32 + blk) * 2 + 0] = a1[0] + a1[1] + a1[2] + a1[3];
        part[(bg * 32 + blk) * 2 + 1] = a2[0] + a2[1] + a2[2] + a2[3];
    }
}

// final reduce + fused GN coefficients: xn = x*ca + cb. grid = 16 (b*8+gi).
__global__ __launch_bounds__(64) void gn_final_coef(
    const float* __restrict__ part, const float* __restrict__ gw,
    const float* __restrict__ gb, float* __restrict__ ca, float* __restrict__ cb)
{
    int bg = blockIdx.x, tid = threadIdx.x;
    float s1 = tid < 32 ? part[(bg * 32 + tid) * 2] : 0.f;
    float s2 = tid < 32 ? part[(bg * 32 + tid) * 2 + 1] : 0.f;
    for (int m = 1; m < 32; m <<= 1) { s1 += __shfl_xor(s1, m); s2 += __shfl_xor(s2, m); }
    const float invN = 1.0f / (64.0f * (float)S_);
    float mu = __shfl(s1, 0) * invN;
    float var = __shfl(s2, 0) * invN - mu * mu;
    float rs = rsqrtf(var + 1e-5f);
    int z = bg >> 3, c = (bg & 7) * 64 + tid;     // channel
    float a = rs * gw[c];
    ca[z * 512 + c] = a;
    cb[z * 512 + c] = gb[c] - mu * a;
}

// ---------------------------------------------------------------- NT-GEMM
// (128^2 tile, 2-barrier dbuf). Still used for MODE 3 (K/V) and MODE 4 (Q).
// LAUNCH-BOUNDS RULE (measured R8/R9): VGPR cap ~= 256/arg2.
template <int MODE, bool SWAP>
__global__ __launch_bounds__(256, 4) void gemm_nt(
    const u16* __restrict__ A, const u16* __restrict__ Bp,
    const float* __restrict__ bias, void* __restrict__ outp,
    const float* __restrict__ resid, int K, int ldo,
    size_t aStride, size_t bStride, size_t oStride, float scale,
    const u16* __restrict__ Bp2, const float* __restrict__ bias2,
    void* __restrict__ outp2)
{
    __shared__ __align__(16) u16 lA[2][4096];
    __shared__ __align__(16) u16 lB[2][4096];
    const int tid = threadIdx.x;
    const int w = tid >> 6, lane = tid & 63;
    const int g = lane >> 4, r = lane & 15;

    const int nx = gridDim.x, nxy = nx * gridDim.y;
    const int raw = blockIdx.x + nx * blockIdx.y;
    const int tile = (raw & 7) * (nxy >> 3) + (raw >> 3);
    const int bx = tile % nx, by = tile / nx;
    const int m0 = (SWAP ? by : bx) * 128, n0 = (SWAP ? bx : by) * 128;
    const int z = blockIdx.z;
    A += (size_t)z * aStride;
    const u16* Bsel = Bp;
    if constexpr (MODE == 3) { if (z) Bsel = Bp2; }
    Bsel += (size_t)z * bStride;

    const int l8 = lane & 7, lh = lane >> 3;
    const int u_ = l8 ^ lh;
    const int mro = (lh << 1) + (u_ >> 2);
    const int kco = (u_ & 3) * 8;
    const int wr = w >> 1, wc = w & 1;
    const int nt = K >> 5;

    f32x4 acc[4][4];
#pragma unroll
    for (int m = 0; m < 4; ++m)
#pragma unroll
        for (int n = 0; n < 4; ++n) acc[m][n] = f32x4{0.f, 0.f, 0.f, 0.f};

#define STAGE_B(t, bi_) {                                                      \
    size_t ko_ = (size_t)((t) * 32 + kco);                                     \
    _Pragma("unroll")                                                          \
    for (int j = 0; j < 2; ++j) {                                              \
        int grow_ = w * 32 + j * 16 + mro;                                     \
        gload16(Bsel + (size_t)(n0 + grow_) * K + ko_,                         \
                &lB[bi_][(w * 16 + j * 8) << 6]);                              \
    } }

#define STAGE_A(t, bi_) {                                                      \
    size_t ko_ = (size_t)((t) * 32 + kco);                                     \
    _Pragma("unroll")                                                          \
    for (int j = 0; j < 2; ++j) {                                              \
        int grow_ = w * 32 + j * 16 + mro;                                     \
        gload16(A + (size_t)(m0 + grow_) * K + ko_,                            \
                &lA[bi_][(w * 16 + j * 8) << 6]);                              \
    } }

    // MODE4 state: fused-GN transposing A staging
    const float* xA = nullptr;
    const float* cAp = nullptr;
    const float* cBp = nullptr;
    int cp2 = 0, sb = 0, zc = 0;
    f32x4 a00{}, a01{}, a10{}, a11{};
    float2 ka{}, kb{};
    if constexpr (MODE == 4) {
        xA = resid + (size_t)z * ((size_t)C_ * S_);
        cAp = bias2;
        cBp = (const float*)outp2;
        cp2 = (tid >> 4) * 2;
        sb = (tid & 15) * 8;
        zc = z * 512;
    }

#define LOAD_A4(t) {                                                           \
    int c0n_ = (t) * 32 + cp2;                                                 \
    const float* r0_ = xA + (size_t)c0n_ * S_ + m0 + sb;                       \
    a00 = *(const f32x4*)r0_;  a01 = *(const f32x4*)(r0_ + 4);                 \
    a10 = *(const f32x4*)(r0_ + S_); a11 = *(const f32x4*)(r0_ + S_ + 4);      \
    ka = *(const float2*)&cAp[zc + c0n_];                                      \
    kb = *(const float2*)&cBp[zc + c0n_]; }

#define WRITE_A4(bi_) {                                                        \
    _Pragma("unroll")                                                          \
    for (int j = 0; j < 8; ++j) {                                              \
        float v0_ = ((j < 4) ? a00[j] : a01[j - 4]) * ka.x + kb.x;             \
        float v1_ = ((j < 4) ? a10[j] : a11[j - 4]) * ka.y + kb.y;             \
        int mm_ = sb + j;                                                      \
        int idx_ = ((mm_ >> 1) << 6)                                           \
            + (((((mm_ & 1) << 2) + (cp2 >> 3)) ^ ((mm_ >> 1) & 7)) << 3)      \
            + (cp2 & 7);                                                       \
        *(u32*)&lA[bi_][idx_] = cvtpk(v0_, v1_);                               \
    } }

    if constexpr (MODE == 4) {
        STAGE_B(0, 0);
        LOAD_A4(0);
        WRITE_A4(0);
    } else {
        STAGE_A(0, 0);
        STAGE_B(0, 0);
    }
    __syncthreads();

    for (int t = 0; t < nt; ++t) {
        const int cur = t & 1;
        if (t + 1 < nt) {
            STAGE_B(t + 1, cur ^ 1);
            if constexpr (MODE == 4) { LOAD_A4(t + 1); }
            else                     { STAGE_A(t + 1, cur ^ 1); }
        }
        bf16x8 af[4], bf_[4];
#pragma unroll
        for (int m = 0; m < 4; ++m) {
            int row = wr * 32 + m * 8 + (r >> 1);
            int slot = (((r & 1) << 2) + g) ^ ((r >> 1) & 7);
            af[m] = *(const bf16x8*)&lA[cur][(row << 6) + (slot << 3)];
        }
#pragma unroll
        for (int n = 0; n < 4; ++n) {
            int row = wc * 32 + n * 8 + (r >> 1);
            int slot = (((r & 1) << 2) + g) ^ ((r >> 1) & 7);
            bf_[n] = *(const bf16x8*)&lB[cur][(row << 6) + (slot << 3)];
        }
#pragma unroll
        for (int m = 0; m < 4; ++m)
#pragma unroll
            for (int n = 0; n < 4; ++n)
                acc[m][n] = mfma16(bf_[n], af[m], acc[m][n]);  // col=m, rows=n
        if constexpr (MODE == 4) { if (t + 1 < nt) WRITE_A4(cur ^ 1); }
        __syncthreads();
    }
#undef STAGE_A
#undef STAGE_B
#undef LOAD_A4
#undef WRITE_A4

    if constexpr (MODE == 0 || MODE == 4) {
        u16* ob = (u16*)outp + (size_t)z * oStride;
#pragma unroll
        for (int m = 0; m < 4; ++m) {
            int gm = m0 + wr * 64 + m * 16 + r;
#pragma unroll
            for (int n = 0; n < 4; ++n) {
                int gn0 = n0 + wc * 64 + n * 16 + g * 4;
                float4 bn = *(const float4*)&bias[gn0];
                u32 w0 = cvtpk(acc[m][n][0] * scale + bn.x * scale,
                               acc[m][n][1] * scale + bn.y * scale);
                u32 w1 = cvtpk(acc[m][n][2] * scale + bn.z * scale,
                               acc[m][n][3] * scale + bn.w * scale);
                *(uint2*)&ob[(size_t)gm * ldo + gn0] = make_uint2(w0, w1);
            }
        }
    } else if constexpr (MODE == 2) {
        float* of = (float*)outp + (size_t)z * oStride;
        const float* rs = resid + (size_t)z * oStride;
#pragma unroll
        for (int m = 0; m < 4; ++m) {
            int gm = m0 + wr * 64 + m * 16 + r;
            float bm = bias[gm];
#pragma unroll
            for (int n = 0; n < 4; ++n) {
                int gn0 = n0 + wc * 64 + n * 16 + g * 4;
                size_t idx = (size_t)gm * ldo + gn0;
                float4 rv = *(const float4*)&rs[idx];
                float4 o4;
                o4.x = acc[m][n][0] + bm + rv.x;
                o4.y = acc[m][n][1] + bm + rv.y;
                o4.z = acc[m][n][2] + bm + rv.z;
                o4.w = acc[m][n][3] + bm + rv.w;
                *(float4*)&of[idx] = o4;
            }
        }
    } else if constexpr (MODE == 3) {
        if (z == 0) {  // K projection: (b*l, o) bf16
            u16* ob = (u16*)outp;
#pragma unroll
            for (int m = 0; m < 4; ++m) {
                int gm = m0 + wr * 64 + m * 16 + r;
#pragma unroll
                for (int n = 0; n < 4; ++n) {
                    int gn0 = n0 + wc * 64 + n * 16 + g * 4;
                    float4 bn = *(const float4*)&bias[gn0];
                    u32 w0 = cvtpk(acc[m][n][0] + bn.x, acc[m][n][1] + bn.y);
                    u32 w1 = cvtpk(acc[m][n][2] + bn.z, acc[m][n][3] + bn.w);
                    *(uint2*)&ob[(size_t)gm * ldo + gn0] = make_uint2(w0, w1);
                }
            }
        } else {       // V projection scattered to (b,h,e,l) bf16
            u16* ob = (u16*)outp2;
#pragma unroll
            for (int m = 0; m < 4; ++m) {
                int gm = m0 + wr * 64 + m * 16 + r;  // ctx row = b*256 + l
                int bb = gm >> 8, l = gm & 255;
#pragma unroll
                for (int n = 0; n < 4; ++n) {
                    int gn0 = n0 + wc * 64 + n * 16 + g * 4;
#pragma unroll
                    for (int i = 0; i < 4; ++i)
                        ob[((size_t)(bb * 512 + gn0 + i)) * 256 + l] =
                            f2b(acc[m][n][i] + bias2[gn0 + i]);
                }
            }
        }
    }
}

// --------------------------------------------- proj GEMM, 256^2 phase-interleaved
// out[m,n] = sum_k wp[m,k]*ao[n,k] + bias[m] + resid[m,n]   (m=512, n=32768, K=512)
// 512 thr / 8 waves (2M x 4N), per-wave 128x64 out, acc[8][4].
// LDS 128KB: L{A,B}[buf][half(128rows)][panel(32k)][128x32 swizzled 8KB].
// Per K-tile (BK=64): 4 phases (output quadrant each): 12 ds_read_b128 +
// (q0: stage A of kt+1, q1: stage B of kt+1) + s_barrier + 16 MFMA + s_barrier.
// One vmcnt(0) per K-tile at q3 (loads issued >=2 phases earlier -> stale).
// Race-free: buffer kt&1^1 written only after kt-1's trailing barrier passed.
__global__ __launch_bounds__(512, 1) void gemm8_proj(
    const u16* __restrict__ Aw, const u16* __restrict__ Bm,
    const float* __restrict__ bias, float* __restrict__ outp,
    const float* __restrict__ resid)
{
    __shared__ __align__(16) u16 LA[2][2][2][4096];
    __shared__ __align__(16) u16 LB[2][2][2][4096];
    const int tid = threadIdx.x;
    const int w = tid >> 6, lane = tid & 63;
    const int g = lane >> 4, r = lane & 15;

    // XCD swizzle over the 2x128 per-z grid (256 tiles, %8==0)
    const int raw = blockIdx.x + 2 * blockIdx.y;
    const int tile = (raw & 7) * 32 + (raw >> 3);
    const int m0 = (tile & 1) * 256, n0 = (tile >> 1) * 256;
    const int z = blockIdx.z;
    const size_t bsc = (size_t)S_ * C_;
    const u16* Bz = Bm + (size_t)z * bsc;

    // staging source pre-swizzle (proven: slot = (l8^lh)^lh = l8 -> linear dest)
    const int l8 = lane & 7, lh = lane >> 3;
    const int u_ = l8 ^ lh;
    const int mro = (lh << 1) + (u_ >> 2);
    const int kco = (u_ & 3) * 8;
    const int grow = w * 16 + mro;          // 0..127 within a half
    const int wr = w >> 2, wc = w & 3;      // wave -> (M-half, N-quarter)

    f32x4 acc[8][4];
#pragma unroll
    for (int mi = 0; mi < 8; ++mi)
#pragma unroll
        for (int ni = 0; ni < 4; ++ni) acc[mi][ni] = f32x4{0.f, 0.f, 0.f, 0.f};

#define STGA(bi, half, panel, kt)                                              \
    gload16(Aw + (size_t)(m0 + (half) * 128 + grow) * 512                      \
                + (kt) * 64 + (panel) * 32 + kco,                              \
            &LA[bi][half][panel][w << 9]);
#define STGB(bi, half, panel, kt)                                              \
    gload16(Bz + (size_t)(n0 + (half) * 128 + grow) * 512                      \
                + (kt) * 64 + (panel) * 32 + kco,                              \
            &LB[bi][half][panel][w << 9]);

    // prologue: stage K-tile 0 fully
    STGA(0, 0, 0, 0); STGA(0, 0, 1, 0); STGA(0, 1, 0, 0); STGA(0, 1, 1, 0);
    STGB(0, 0, 0, 0); STGB(0, 0, 1, 0); STGB(0, 1, 0, 0); STGB(0, 1, 1, 0);
    asm volatile("s_waitcnt vmcnt(0)" ::: "memory");
    __builtin_amdgcn_s_barrier();

    const int fro = r >> 1;
    const int sl = (((r & 1) << 2) + g) ^ ((r >> 1) & 7);

    for (int kt = 0; kt < 8; ++kt) {
        const int buf = kt & 1, nb = buf ^ 1;
        const bool more = (kt + 1 < 8);
#pragma unroll
        for (int q = 0; q < 4; ++q) {
            const int mh = q >> 1, nh = q & 1;
            bf16x8 af[4][2], bf[2][2];
#pragma unroll
            for (int i = 0; i < 4; ++i)
#pragma unroll
                for (int kk = 0; kk < 2; ++kk)
                    af[i][kk] = *(const bf16x8*)
                        &LA[buf][wr][kk][(((mh * 4 + i) * 8 + fro) << 6) + (sl << 3)];
#pragma unroll
            for (int j = 0; j < 2; ++j)
#pragma unroll
                for (int kk = 0; kk < 2; ++kk)
                    bf[j][kk] = *(const bf16x8*)
                        &LB[buf][wc >> 1][kk]
                           [((((wc & 1) * 4 + nh * 2 + j) * 8 + fro) << 6) + (sl << 3)];
            if (more) {
                if (q == 0) {
                    STGA(nb, 0, 0, kt + 1); STGA(nb, 0, 1, kt + 1);
                    STGA(nb, 1, 0, kt + 1); STGA(nb, 1, 1, kt + 1);
                } else if (q == 1) {
                    STGB(nb, 0, 0, kt + 1); STGB(nb, 0, 1, kt + 1);
                    STGB(nb, 1, 0, kt + 1); STGB(nb, 1, 1, kt + 1);
                }
            }
            __builtin_amdgcn_s_barrier();
            __builtin_amdgcn_s_setprio(1);
#pragma unroll
            for (int i = 0; i < 4; ++i)
#pragma unroll
                for (int j = 0; j < 2; ++j)
#pragma unroll
                    for (int kk = 0; kk < 2; ++kk)
                        acc[mh * 4 + i][nh * 2 + j] =
                            mfma16(bf[j][kk], af[i][kk], acc[mh * 4 + i][nh * 2 + j]);
            __builtin_amdgcn_s_setprio(0);
            if (q == 3 && more) asm volatile("s_waitcnt vmcnt(0)" ::: "memory");
            __builtin_amdgcn_s_barrier();
        }
    }
#undef STGA
#undef STGB

    float* of = outp + (size_t)z * bsc;
    const float* rs = resid + (size_t)z * bsc;
#pragma unroll
    for (int mi = 0; mi < 8; ++mi) {
        int gm = m0 + wr * 128 + mi * 16 + r;
        float bm = bias[gm];
#pragma unroll
        for (int ni = 0; ni < 4; ++ni) {
            int gn0 = n0 + wc * 64 + ni * 16 + g * 4;
            size_t idx = (size_t)gm * S_ + gn0;
            float4 rv = *(const float4*)&rs[idx];
            float4 o4;
            o4.x = acc[mi][ni][0] + bm + rv.x;
            o4.y = acc[mi][ni][1] + bm + rv.y;
            o4.z = acc[mi][ni][2] + bm + rv.z;
            o4.w = acc[mi][ni][3] + bm + rv.w;
            *(float4*)&of[idx] = o4;
        }
    }
}

// ---------------------------------------------------------------- attention
// (unchanged from R10; (512,2) bounds to avoid the 64-VGPR spill cap)
__global__ __launch_bounds__(512, 2) void attn_kernel(
    const u16* __restrict__ q, const u16* __restrict__ kk,
    const u16* __restrict__ vv, u16* __restrict__ ao)
{
    __shared__ __align__(16) u16 sm[32768];
    const int tid = threadIdx.x;
    const int w = tid >> 6, lane = tid & 63;
    const int g = lane >> 4, r = lane & 15;
    const int bh = blockIdx.y, b = bh >> 3, h = bh & 7;
    const int s0 = blockIdx.x * 256;

    {   // stage K (b,l,h*64+e) rows -> sm[l*64 + swz]
        const u16* kbase = kk + ((size_t)b * L_) * C_ + h * 64;
#pragma unroll
        for (int j = 0; j < 4; ++j) {
            int idx = j * 512 + tid;
            int l = idx >> 3, ch = idx & 7;
            u16x8 val = *(const u16x8*)(kbase + (size_t)l * C_ + ch * 8);
            *(u16x8*)&sm[l * 64 + ((ch ^ (l & 7)) << 3)] = val;
        }
        // stage V (b,h,e,l) rows -> sm[16384 + e*256 + swz]
        const u16* vbase = vv + ((size_t)bh * 64) * 256;
#pragma unroll
        for (int j = 0; j < 4; ++j) {
            int idx = j * 512 + tid;
            int e = idx >> 5, ch = idx & 31;
            u16x8 val = *(const u16x8*)(vbase + (size_t)e * 256 + ch * 8);
            *(u16x8*)&sm[16384 + e * 256 + ((ch ^ (e & 7)) << 3)] = val;
        }
    }

    // Q fragments straight from global (read-once)
    const int sw = s0 + w * 32;
    bf16x8 qf[2][2];
#pragma unroll
    for (int m = 0; m < 2; ++m)
#pragma unroll
        for (int kt = 0; kt < 2; ++kt)
            qf[m][kt] = *(const bf16x8*)(q + ((size_t)(b * S_ + sw + m * 16 + r)) * C_
                                         + h * 64 + kt * 32 + g * 8);
    __syncthreads();

    // QK^T swapped: accs[m][n][i] = P[s = m*16 + r][l = n*16 + g*4 + i]
    f32x4 accs[2][16];
#pragma unroll
    for (int m = 0; m < 2; ++m)
#pragma unroll
        for (int n = 0; n < 16; ++n) accs[m][n] = f32x4{0.f, 0.f, 0.f, 0.f};
    __builtin_amdgcn_s_setprio(1);
#pragma unroll
    for (int n = 0; n < 16; ++n) {
#pragma unroll
        for (int kt = 0; kt < 2; ++kt) {
            int c = kt * 4 + g;  // e-chunk index
            bf16x8 kf = *(const bf16x8*)&sm[(n * 16 + r) * 64 + ((c ^ (r & 7)) << 3)];
#pragma unroll
            for (int m = 0; m < 2; ++m) accs[m][n] = mfma16(kf, qf[m][kt], accs[m][n]);
        }
    }
    __builtin_amdgcn_s_setprio(0);

    // softmax: in-lane over 64 values, cross-lane over the 4 lanes sharing r
    float inv[2];
#pragma unroll
    for (int m = 0; m < 2; ++m) {
        float mx = accs[m][0][0];
#pragma unroll
        for (int n = 0; n < 16; ++n)
#pragma unroll
            for (int i = 0; i < 4; ++i) mx = fmaxf(mx, accs[m][n][i]);
        mx = fmaxf(mx, __shfl_xor(mx, 16));
        mx = fmaxf(mx, __shfl_xor(mx, 32));
        float sum = 0.f;
#pragma unroll
        for (int n = 0; n < 16; ++n)
#pragma unroll
            for (int i = 0; i < 4; ++i) {
                float e = __expf(accs[m][n][i] - mx);
                accs[m][n][i] = e; sum += e;
            }
        sum += __shfl_xor(sum, 16);
        sum += __shfl_xor(sum, 32);
        inv[m] = 1.0f / sum;
    }

    // PV: per l-chunk c, repack P in-register into fragments, then MFMA.
    f32x4 acco[2][4];
#pragma unroll
    for (int m = 0; m < 2; ++m)
#pragma unroll
        for (int n = 0; n < 4; ++n) acco[m][n] = f32x4{0.f, 0.f, 0.f, 0.f};

#pragma unroll
    for (int c = 0; c < 8; ++c) {
        bf16x8 pa[2];
#pragma unroll
        for (int m = 0; m < 2; ++m) {
            u32 x0 = cvtpk(accs[m][2 * c][0] * inv[m], accs[m][2 * c][1] * inv[m]);
            u32 x1 = cvtpk(accs[m][2 * c][2] * inv[m], accs[m][2 * c][3] * inv[m]);
            u32 y0 = cvtpk(accs[m][2 * c + 1][0] * inv[m], accs[m][2 * c + 1][1] * inv[m]);
            u32 y1 = cvtpk(accs[m][2 * c + 1][2] * inv[m], accs[m][2 * c + 1][3] * inv[m]);
            pl32(x0, y0);
            pl32(x1, y1);
            pl16(x0, y0);
            pl16(x1, y1);
            u32x4 pw; pw[0] = x0; pw[1] = x1; pw[2] = y0; pw[3] = y1;
            pa[m] = *(bf16x8*)&pw;
        }
        bf16x8 vf[4];
#pragma unroll
        for (int n = 0; n < 4; ++n) {
            int e = n * 16 + r;
            vf[n] = *(const bf16x8*)&sm[16384 + e * 256 + (((c * 4 + g) ^ (r & 7)) << 3)];
        }
        __builtin_amdgcn_s_setprio(1);
#pragma unroll
        for (int m = 0; m < 2; ++m)
#pragma unroll
            for (int n = 0; n < 4; ++n)
                acco[m][n] = mfma16(vf[n], pa[m], acco[m][n]);  // col=s, rows=e
        __builtin_amdgcn_s_setprio(0);
    }

    // write attention output as (b, s, c=h*64+e) bf16, 8B per store
#pragma unroll
    for (int m = 0; m < 2; ++m) {
        const size_t rowb = ((size_t)(b * S_ + sw + m * 16 + r)) * C_ + h * 64;
#pragma unroll
        for (int n = 0; n < 4; ++n) {
            u32 w0 = cvtpk(acco[m][n][0], acco[m][n][1]);
            u32 w1 = cvtpk(acco[m][n][2], acco[m][n][3]);
            *(uint2*)&ao[rowb + n * 16 + g * 4] = make_uint2(w0, w1);
        }
    }
}

// ---------------------------------------------------------------- launch
extern "C" void kernel_launch(void* const* d_in, const int* in_sizes, int n_in,
                              void* d_out, int out_size, void* d_ws, size_t ws_size,
                              hipStream_t stream)
{
    (void)in_sizes; (void)n_in; (void)out_size; (void)ws_size;
    const float* x    = (const float*)d_in[0];
    const float* ctx  = (const float*)d_in[1];
    const float* gn_w = (const float*)d_in[2];
    const float* gn_b = (const float*)d_in[3];
    const float* ln_w = (const float*)d_in[4];
    const float* ln_b = (const float*)d_in[5];
    const float* q_w  = (const float*)d_in[6];
    const float* q_b  = (const float*)d_in[7];
    const float* k_w  = (const float*)d_in[8];
    const float* k_b  = (const float*)d_in[9];
    const float* v_w  = (const float*)d_in[10];
    const float* v_b  = (const float*)d_in[11];
    const float* p_w  = (const float*)d_in[12];
    const float* p_b  = (const float*)d_in[13];
    float* out = (float*)d_out;

    char* ws = (char*)d_ws;
    constexpr size_t WS_WQ   = 0;
    constexpr size_t WS_WK   = WS_WQ + (size_t)512 * 512 * 2;
    constexpr size_t WS_WV   = WS_WK + (size_t)512 * 768 * 2;
    constexpr size_t WS_WP   = WS_WV + (size_t)512 * 768 * 2;
    constexpr size_t WS_PART = WS_WP + (size_t)512 * 512 * 2;
    constexpr size_t WS_CA   = WS_PART + (size_t)16 * 64 * 2 * 4;
    constexpr size_t WS_CB   = WS_CA + 4096;
    constexpr size_t WS_CTXN = WS_CB + 4096;
    constexpr size_t WS_K    = WS_CTXN + (size_t)512 * 768 * 2;
    constexpr size_t WS_V    = WS_K + (size_t)2 * 8 * 256 * 64 * 2;
    constexpr size_t WS_Q    = WS_V + (size_t)2 * 8 * 256 * 64 * 2;
    constexpr size_t WS_H    = WS_Q + (size_t)2 * 32768 * 512 * 2;

    u16* wq = (u16*)(ws + WS_WQ);
    u16* wk = (u16*)(ws + WS_WK);
    u16* wv = (u16*)(ws + WS_WV);
    u16* wp = (u16*)(ws + WS_WP);
    float* part  = (float*)(ws + WS_PART);
    float* coefA = (float*)(ws + WS_CA);
    float* coefB = (float*)(ws + WS_CB);
    u16* ctxn = (u16*)(ws + WS_CTXN);
    u16* kt   = (u16*)(ws + WS_K);
    u16* vt   = (u16*)(ws + WS_V);
    u16* qt   = (u16*)(ws + WS_Q);
    u16* ao   = (u16*)(ws + WS_H);  // attention output buffer

    const size_t bsc = (size_t)S_ * C_;  // per-batch (s,c)/(c,s) stride

    gn_partial<<<dim3(32, 16), 256, 0, stream>>>(x, part);
    prep_small<<<dim3(512, 5), 256, 0, stream>>>(q_w, k_w, v_w, p_w,
                                                 wq, wk, wv, wp,
                                                 ctx, ln_w, ln_b, ctxn);
    gn_final_coef<<<16, 64, 0, stream>>>(part, gn_w, gn_b, coefA, coefB);
    // Q = GN(x) . Wq^T fused (scale folded), out (b,s,o) bf16.
    gemm_nt<4, true><<<dim3(4, 256, 2), 256, 0, stream>>>(
        nullptr, wq, q_b, qt, x, 512, 512, 0, 0, bsc, 0.125f,
        nullptr, coefA, coefB);
    // K,V = ctxn . W^T in one launch (z selects)
    gemm_nt<3, false><<<dim3(4, 4, 2), 256, 0, stream>>>(
        ctxn, wk, k_b, kt, nullptr, 768, 512, 0, 0, 0, 1.0f,
        wv, v_b, vt);
    attn_kernel<<<dim3(128, 16), 512, 0, stream>>>(qt, kt, vt, ao);
    // out = Wp . ao^T + bias + x (fp32, (b,c,s)) -- 256^2 phase-interleaved
    gemm8_proj<<<dim3(2, 128, 2), 512, 0, stream>>>(wp, ao, p_b, out, x);
}

// Round 12
// 268.148 us; speedup vs baseline: 1.0704x; 1.0704x over previous
//
#include <hip/hip_runtime.h>

typedef unsigned short u16;
typedef unsigned int u32;
typedef __attribute__((ext_vector_type(4))) float f32x4;
typedef __attribute__((ext_vector_type(8))) short bf16x8;
typedef __attribute__((ext_vector_type(8))) u16 u16x8;
typedef __attribute__((ext_vector_type(4))) u16 u16x4;
typedef __attribute__((ext_vector_type(4))) u32 u32x4;

#define DEVI __device__ __forceinline__

constexpr int C_ = 512, S_ = 32768, L_ = 256, CTX_ = 768;

DEVI u16 f2b(float f) {  // fp32 -> bf16 RNE
    union { float f; unsigned u; } x; x.f = f;
    unsigned r = x.u + 0x7fffu + ((x.u >> 16) & 1u);
    return (u16)(r >> 16);
}

DEVI f32x4 mfma16(bf16x8 a, bf16x8 b, f32x4 c) {
    return __builtin_amdgcn_mfma_f32_16x16x32_bf16(a, b, c, 0, 0, 0);
}

DEVI void gload16(const void* g, void* l) {
    __builtin_amdgcn_global_load_lds(
        (const __attribute__((address_space(1))) void*)g,
        (__attribute__((address_space(3))) void*)l, 16, 0, 0);
}

DEVI u32 cvtpk(float lo, float hi) {  // word = (bf16(hi)<<16) | bf16(lo)
    u32 d;
    asm("v_cvt_pk_bf16_f32 %0, %1, %2" : "=v"(d) : "v"(lo), "v"(hi));
    return d;
}
DEVI void pl32(u32& a, u32& b) {
    asm volatile("v_permlane32_swap_b32 %0, %1" : "+v"(a), "+v"(b));
}
DEVI void pl16(u32& a, u32& b) {
    asm volatile("v_permlane16_swap_b32 %0, %1" : "+v"(a), "+v"(b));
}

// ------------------------------------- weights cvt + LayerNorm(ctx) merged
__global__ __launch_bounds__(256) void prep_small(
    const float* __restrict__ a0, const float* __restrict__ a1,
    const float* __restrict__ a2, const float* __restrict__ a3,
    u16* __restrict__ o0, u16* __restrict__ o1,
    u16* __restrict__ o2, u16* __restrict__ o3,
    const float* __restrict__ ctx, const float* __restrict__ lw,
    const float* __restrict__ lb, u16* __restrict__ cn)
{
    const int which = blockIdx.y, tid = threadIdx.x;
    if (which < 4) {
        const float* src = which == 0 ? a0 : which == 1 ? a1 : which == 2 ? a2 : a3;
        u16* dst = which == 0 ? o0 : which == 1 ? o1 : which == 2 ? o2 : o3;
        int n4 = (which == 1 || which == 2) ? (512 * 768 / 4) : (512 * 512 / 4);
        int i = blockIdx.x * 256 + tid;
        if (i < n4) {
            float4 v = ((const float4*)src)[i];
            u16x4 o; o[0] = f2b(v.x); o[1] = f2b(v.y); o[2] = f2b(v.z); o[3] = f2b(v.w);
            ((u16x4*)dst)[i] = o;
        }
        return;
    }
    // LayerNorm over ctx rows
    const int row = blockIdx.x;
    const float* p = ctx + (size_t)row * CTX_;
    float v0 = p[tid], v1 = p[tid + 256], v2 = p[tid + 512];
    float s1 = v0 + v1 + v2, s2 = v0 * v0 + v1 * v1 + v2 * v2;
    for (int m = 1; m < 64; m <<= 1) { s1 += __shfl_xor(s1, m); s2 += __shfl_xor(s2, m); }
    __shared__ float a1s[4], a2s[4];
    int w = tid >> 6, lane = tid & 63;
    if (lane == 0) { a1s[w] = s1; a2s[w] = s2; }
    __syncthreads();
    s1 = a1s[0] + a1s[1] + a1s[2] + a1s[3];
    s2 = a2s[0] + a2s[1] + a2s[2] + a2s[3];
    const float invN = 1.0f / 768.0f;
    float mu = s1 * invN, rstd = rsqrtf(s2 * invN - mu * mu + 1e-5f);
    u16* o = cn + (size_t)row * CTX_;
    o[tid]       = f2b((v0 - mu) * rstd * lw[tid]       + lb[tid]);
    o[tid + 256] = f2b((v1 - mu) * rstd * lw[tid + 256] + lb[tid + 256]);
    o[tid + 512] = f2b((v2 - mu) * rstd * lw[tid + 512] + lb[tid + 512]);
}

// ---------------------------------------------------------------- GN stats
// grid (64, 16): x-split = 2 c-halves x 32 s-blocks -> 1024 blocks (4/CU).
__global__ __launch_bounds__(256) void gn_partial(const float* __restrict__ x,
                                                  float* __restrict__ part)
{
    const int bg = blockIdx.y, blk = blockIdx.x, tid = threadIdx.x;
    const int cs = blk >> 5, sblk = blk & 31;
    const float* base = x + (size_t)(bg * 64 + cs * 32) * S_
                          + (size_t)sblk * 1024 + tid * 4;
    float s1 = 0.f, s2 = 0.f;
    for (int c = 0; c < 32; ++c) {
        float4 v = *(const float4*)(base + (size_t)c * S_);
        s1 += v.x + v.y + v.z + v.w;
        s2 += v.x * v.x + v.y * v.y + v.z * v.z + v.w * v.w;
    }
    for (int m = 1; m < 64; m <<= 1) { s1 += __shfl_xor(s1, m); s2 += __shfl_xor(s2, m); }
    __shared__ float a1[4], a2[4];
    int w = tid >> 6, lane = tid & 63;
    if (lane == 0) { a1[w] = s1; a2[w] = s2; }
    __syncthreads();
    if (tid == 0) {
        part[(bg * 64 + blk) * 2 + 0] = a1[0] + a1[1] + a1[2] + a1[3];
        part[(bg * 64 + blk) * 2 + 1] = a2[0] + a2[1] + a2[2] + a2[3];
    }
}

// final reduce + fused GN coefficients: xn = x*ca + cb. grid = 16 (b*8+gi).
__global__ __launch_bounds__(64) void gn_final_coef(
    const float* __restrict__ part, const float* __restrict__ gw,
    const float* __restrict__ gb, float* __restrict__ ca, float* __restrict__ cb)
{
    int bg = blockIdx.x, tid = threadIdx.x;
    float s1 = part[(bg * 64 + tid) * 2];
    float s2 = part[(bg * 64 + tid) * 2 + 1];
    for (int m = 1; m < 64; m <<= 1) { s1 += __shfl_xor(s1, m); s2 += __shfl_xor(s2, m); }
    const float invN = 1.0f / (64.0f * (float)S_);
    float mu = __shfl(s1, 0) * invN;
    float var = __shfl(s2, 0) * invN - mu * mu;
    float rs = rsqrtf(var + 1e-5f);
    int z = bg >> 3, c = (bg & 7) * 64 + tid;     // channel
    float a = rs * gw[c];
    ca[z * 512 + c] = a;
    cb[z * 512 + c] = gb[c] - mu * a;
}

// ---------------------------------------------------------------- NT-GEMM
// (128^2 tile, 2-barrier dbuf). MODE 3 (K/V), MODE 4 (Q), MODE 2 (proj).
// LAUNCH-BOUNDS RULE (measured R8/R9): VGPR cap ~= 256/arg2. (256,4) -> 64,
// exactly this kernel's fit; do not raise arg2.
// NOTE (R11): proj is schedule-insensitive (2-barrier == counted-vmcnt ==
// 8-phase 256^2, all 97+-2us) -- low-AI streaming GEMM, not MFMA-limited.
template <int MODE, bool SWAP>
__global__ __launch_bounds__(256, 4) void gemm_nt(
    const u16* __restrict__ A, const u16* __restrict__ Bp,
    const float* __restrict__ bias, void* __restrict__ outp,
    const float* __restrict__ resid, int K, int ldo,
    size_t aStride, size_t bStride, size_t oStride, float scale,
    const u16* __restrict__ Bp2, const float* __restrict__ bias2,
    void* __restrict__ outp2)
{
    __shared__ __align__(16) u16 lA[2][4096];
    __shared__ __align__(16) u16 lB[2][4096];
    const int tid = threadIdx.x;
    const int w = tid >> 6, lane = tid & 63;
    const int g = lane >> 4, r = lane & 15;

    const int nx = gridDim.x, nxy = nx * gridDim.y;
    const int raw = blockIdx.x + nx * blockIdx.y;
    const int tile = (raw & 7) * (nxy >> 3) + (raw >> 3);
    const int bx = tile % nx, by = tile / nx;
    const int m0 = (SWAP ? by : bx) * 128, n0 = (SWAP ? bx : by) * 128;
    const int z = blockIdx.z;
    A += (size_t)z * aStride;
    const u16* Bsel = Bp;
    if constexpr (MODE == 3) { if (z) Bsel = Bp2; }
    Bsel += (size_t)z * bStride;

    const int l8 = lane & 7, lh = lane >> 3;
    const int u_ = l8 ^ lh;
    const int mro = (lh << 1) + (u_ >> 2);
    const int kco = (u_ & 3) * 8;
    const int wr = w >> 1, wc = w & 1;
    const int nt = K >> 5;

    f32x4 acc[4][4];
#pragma unroll
    for (int m = 0; m < 4; ++m)
#pragma unroll
        for (int n = 0; n < 4; ++n) acc[m][n] = f32x4{0.f, 0.f, 0.f, 0.f};

#define STAGE_B(t, bi_) {                                                      \
    size_t ko_ = (size_t)((t) * 32 + kco);                                     \
    _Pragma("unroll")                                                          \
    for (int j = 0; j < 2; ++j) {                                              \
        int grow_ = w * 32 + j * 16 + mro;                                     \
        gload16(Bsel + (size_t)(n0 + grow_) * K + ko_,                         \
                &lB[bi_][(w * 16 + j * 8) << 6]);                              \
    } }

#define STAGE_A(t, bi_) {                                                      \
    size_t ko_ = (size_t)((t) * 32 + kco);                                     \
    _Pragma("unroll")                                                          \
    for (int j = 0; j < 2; ++j) {                                              \
        int grow_ = w * 32 + j * 16 + mro;                                     \
        gload16(A + (size_t)(m0 + grow_) * K + ko_,                            \
                &lA[bi_][(w * 16 + j * 8) << 6]);                              \
    } }

    // MODE4 state: fused-GN transposing A staging
    const float* xA = nullptr;
    const float* cAp = nullptr;
    const float* cBp = nullptr;
    int cp2 = 0, sb = 0, zc = 0;
    f32x4 a00{}, a01{}, a10{}, a11{};
    float2 ka{}, kb{};
    if constexpr (MODE == 4) {
        xA = resid + (size_t)z * ((size_t)C_ * S_);
        cAp = bias2;
        cBp = (const float*)outp2;
        cp2 = (tid >> 4) * 2;
        sb = (tid & 15) * 8;
        zc = z * 512;
    }

#define LOAD_A4(t) {                                                           \
    int c0n_ = (t) * 32 + cp2;                                                 \
    const float* r0_ = xA + (size_t)c0n_ * S_ + m0 + sb;                       \
    a00 = *(const f32x4*)r0_;  a01 = *(const f32x4*)(r0_ + 4);                 \
    a10 = *(const f32x4*)(r0_ + S_); a11 = *(const f32x4*)(r0_ + S_ + 4);      \
    ka = *(const float2*)&cAp[zc + c0n_];                                      \
    kb = *(const float2*)&cBp[zc + c0n_]; }

#define WRITE_A4(bi_) {                                                        \
    _Pragma("unroll")                                                          \
    for (int j = 0; j < 8; ++j) {                                              \
        float v0_ = ((j < 4) ? a00[j] : a01[j - 4]) * ka.x + kb.x;             \
        float v1_ = ((j < 4) ? a10[j] : a11[j - 4]) * ka.y + kb.y;             \
        int mm_ = sb + j;                                                      \
        int idx_ = ((mm_ >> 1) << 6)                                           \
            + (((((mm_ & 1) << 2) + (cp2 >> 3)) ^ ((mm_ >> 1) & 7)) << 3)      \
            + (cp2 & 7);                                                       \
        *(u32*)&lA[bi_][idx_] = cvtpk(v0_, v1_);                               \
    } }

    if constexpr (MODE == 4) {
        STAGE_B(0, 0);
        LOAD_A4(0);
        WRITE_A4(0);
    } else {
        STAGE_A(0, 0);
        STAGE_B(0, 0);
    }
    __syncthreads();

    for (int t = 0; t < nt; ++t) {
        const int cur = t & 1;
        if (t + 1 < nt) {
            STAGE_B(t + 1, cur ^ 1);
            if constexpr (MODE == 4) { LOAD_A4(t + 1); }
            else                     { STAGE_A(t + 1, cur ^ 1); }
        }
        bf16x8 af[4], bf_[4];
#pragma unroll
        for (int m = 0; m < 4; ++m) {
            int row = wr * 32 + m * 8 + (r >> 1);
            int slot = (((r & 1) << 2) + g) ^ ((r >> 1) & 7);
            af[m] = *(const bf16x8*)&lA[cur][(row << 6) + (slot << 3)];
        }
#pragma unroll
        for (int n = 0; n < 4; ++n) {
            int row = wc * 32 + n * 8 + (r >> 1);
            int slot = (((r & 1) << 2) + g) ^ ((r >> 1) & 7);
            bf_[n] = *(const bf16x8*)&lB[cur][(row << 6) + (slot << 3)];
        }
#pragma unroll
        for (int m = 0; m < 4; ++m)
#pragma unroll
            for (int n = 0; n < 4; ++n)
                acc[m][n] = mfma16(bf_[n], af[m], acc[m][n]);  // col=m, rows=n
        if constexpr (MODE == 4) { if (t + 1 < nt) WRITE_A4(cur ^ 1); }
        __syncthreads();
    }
#undef STAGE_A
#undef STAGE_B
#undef LOAD_A4
#undef WRITE_A4

    if constexpr (MODE == 0 || MODE == 4) {
        u16* ob = (u16*)outp + (size_t)z * oStride;
#pragma unroll
        for (int m = 0; m < 4; ++m) {
            int gm = m0 + wr * 64 + m * 16 + r;
#pragma unroll
            for (int n = 0; n < 4; ++n) {
                int gn0 = n0 + wc * 64 + n * 16 + g * 4;
                float4 bn = *(const float4*)&bias[gn0];
                u32 w0 = cvtpk(acc[m][n][0] * scale + bn.x * scale,
                               acc[m][n][1] * scale + bn.y * scale);
                u32 w1 = cvtpk(acc[m][n][2] * scale + bn.z * scale,
                               acc[m][n][3] * scale + bn.w * scale);
                *(uint2*)&ob[(size_t)gm * ldo + gn0] = make_uint2(w0, w1);
            }
        }
    } else if constexpr (MODE == 2) {
        float* of = (float*)outp + (size_t)z * oStride;
        const float* rs = resid + (size_t)z * oStride;
#pragma unroll
        for (int m = 0; m < 4; ++m) {
            int gm = m0 + wr * 64 + m * 16 + r;
            float bm = bias[gm];
#pragma unroll
            for (int n = 0; n < 4; ++n) {
                int gn0 = n0 + wc * 64 + n * 16 + g * 4;
                size_t idx = (size_t)gm * ldo + gn0;
                float4 rv = *(const float4*)&rs[idx];
                float4 o4;
                o4.x = acc[m][n][0] + bm + rv.x;
                o4.y = acc[m][n][1] + bm + rv.y;
                o4.z = acc[m][n][2] + bm + rv.z;
                o4.w = acc[m][n][3] + bm + rv.w;
                *(float4*)&of[idx] = o4;
            }
        }
    } else if constexpr (MODE == 3) {
        if (z == 0) {  // K projection: (b*l, o) bf16
            u16* ob = (u16*)outp;
#pragma unroll
            for (int m = 0; m < 4; ++m) {
                int gm = m0 + wr * 64 + m * 16 + r;
#pragma unroll
                for (int n = 0; n < 4; ++n) {
                    int gn0 = n0 + wc * 64 + n * 16 + g * 4;
                    float4 bn = *(const float4*)&bias[gn0];
                    u32 w0 = cvtpk(acc[m][n][0] + bn.x, acc[m][n][1] + bn.y);
                    u32 w1 = cvtpk(acc[m][n][2] + bn.z, acc[m][n][3] + bn.w);
                    *(uint2*)&ob[(size_t)gm * ldo + gn0] = make_uint2(w0, w1);
                }
            }
        } else {       // V projection scattered to (b,h,e,l) bf16
            u16* ob = (u16*)outp2;
#pragma unroll
            for (int m = 0; m < 4; ++m) {
                int gm = m0 + wr * 64 + m * 16 + r;  // ctx row = b*256 + l
                int bb = gm >> 8, l = gm & 255;
#pragma unroll
                for (int n = 0; n < 4; ++n) {
                    int gn0 = n0 + wc * 64 + n * 16 + g * 4;
#pragma unroll
                    for (int i = 0; i < 4; ++i)
                        ob[((size_t)(bb * 512 + gn0 + i)) * 256 + l] =
                            f2b(acc[m][n][i] + bias2[gn0 + i]);
                }
            }
        }
    }
}

// ---------------------------------------------------------------- attention
// R7-proven 256-thread version. Swapped-QK^T: lane holds P[s][l in regs].
// K AND V staged in LDS (64 KB), read once per block. (256,2) bounds:
// VGPR ~104 fits the 128 cap; LDS limits 2 blocks/CU.
// grid: (S/128, B*NH). 4 waves, 32 s-rows each.
__global__ __launch_bounds__(256, 2) void attn_kernel(
    const u16* __restrict__ q, const u16* __restrict__ kk,
    const u16* __restrict__ vv, u16* __restrict__ ao)
{
    __shared__ __align__(16) u16 sm[32768];
    const int tid = threadIdx.x;
    const int w = tid >> 6, lane = tid & 63;
    const int g = lane >> 4, r = lane & 15;
    const int bh = blockIdx.y, b = bh >> 3, h = bh & 7;
    const int s0 = blockIdx.x * 128;

    {   // stage K (b,l,h*64+e) rows -> sm[l*64 + swz]
        const u16* kbase = kk + ((size_t)b * L_) * C_ + h * 64;
#pragma unroll
        for (int j = 0; j < 8; ++j) {
            int idx = j * 256 + tid;
            int l = idx >> 3, ch = idx & 7;
            u16x8 val = *(const u16x8*)(kbase + (size_t)l * C_ + ch * 8);
            *(u16x8*)&sm[l * 64 + ((ch ^ (l & 7)) << 3)] = val;
        }
        // stage V (b,h,e,l) rows -> sm[16384 + e*256 + swz]
        const u16* vbase = vv + ((size_t)bh * 64) * 256;
#pragma unroll
        for (int j = 0; j < 8; ++j) {
            int idx = j * 256 + tid;
            int e = idx >> 5, ch = idx & 31;
            u16x8 val = *(const u16x8*)(vbase + (size_t)e * 256 + ch * 8);
            *(u16x8*)&sm[16384 + e * 256 + ((ch ^ (e & 7)) << 3)] = val;
        }
    }

    // Q fragments straight from global (read-once)
    const int sw = s0 + w * 32;
    bf16x8 qf[2][2];
#pragma unroll
    for (int m = 0; m < 2; ++m)
#pragma unroll
        for (int kt = 0; kt < 2; ++kt)
            qf[m][kt] = *(const bf16x8*)(q + ((size_t)(b * S_ + sw + m * 16 + r)) * C_
                                         + h * 64 + kt * 32 + g * 8);
    __syncthreads();

    // QK^T swapped: accs[m][n][i] = P[s = m*16 + r][l = n*16 + g*4 + i]
    f32x4 accs[2][16];
#pragma unroll
    for (int m = 0; m < 2; ++m)
#pragma unroll
        for (int n = 0; n < 16; ++n) accs[m][n] = f32x4{0.f, 0.f, 0.f, 0.f};
    __builtin_amdgcn_s_setprio(1);
#pragma unroll
    for (int n = 0; n < 16; ++n) {
#pragma unroll
        for (int kt = 0; kt < 2; ++kt) {
            int c = kt * 4 + g;  // e-chunk index
            bf16x8 kf = *(const bf16x8*)&sm[(n * 16 + r) * 64 + ((c ^ (r & 7)) << 3)];
#pragma unroll
            for (int m = 0; m < 2; ++m) accs[m][n] = mfma16(kf, qf[m][kt], accs[m][n]);
        }
    }
    __builtin_amdgcn_s_setprio(0);

    // softmax: in-lane over 64 values, cross-lane over the 4 lanes sharing r
    float inv[2];
#pragma unroll
    for (int m = 0; m < 2; ++m) {
        float mx = accs[m][0][0];
#pragma unroll
        for (int n = 0; n < 16; ++n)
#pragma unroll
            for (int i = 0; i < 4; ++i) mx = fmaxf(mx, accs[m][n][i]);
        mx = fmaxf(mx, __shfl_xor(mx, 16));
        mx = fmaxf(mx, __shfl_xor(mx, 32));
        float sum = 0.f;
#pragma unroll
        for (int n = 0; n < 16; ++n)
#pragma unroll
            for (int i = 0; i < 4; ++i) {
                float e = __expf(accs[m][n][i] - mx);
                accs[m][n][i] = e; sum += e;
            }
        sum += __shfl_xor(sum, 16);
        sum += __shfl_xor(sum, 32);
        inv[m] = 1.0f / sum;
    }

    // PV: per l-chunk c, repack P in-register into fragments, then MFMA.
    // Operand-swapped: acco[m][n]: col(r) = s, rows(g*4+i) = e.
    f32x4 acco[2][4];
#pragma unroll
    for (int m = 0; m < 2; ++m)
#pragma unroll
        for (int n = 0; n < 4; ++n) acco[m][n] = f32x4{0.f, 0.f, 0.f, 0.f};

#pragma unroll
    for (int c = 0; c < 8; ++c) {
        bf16x8 pa[2];
#pragma unroll
        for (int m = 0; m < 2; ++m) {
            u32 x0 = cvtpk(accs[m][2 * c][0] * inv[m], accs[m][2 * c][1] * inv[m]);
            u32 x1 = cvtpk(accs[m][2 * c][2] * inv[m], accs[m][2 * c][3] * inv[m]);
            u32 y0 = cvtpk(accs[m][2 * c + 1][0] * inv[m], accs[m][2 * c + 1][1] * inv[m]);
            u32 y1 = cvtpk(accs[m][2 * c + 1][2] * inv[m], accs[m][2 * c + 1][3] * inv[m]);
            pl32(x0, y0);
            pl32(x1, y1);
            pl16(x0, y0);
            pl16(x1, y1);
            u32x4 pw; pw[0] = x0; pw[1] = x1; pw[2] = y0; pw[3] = y1;
            pa[m] = *(bf16x8*)&pw;
        }
        bf16x8 vf[4];
#pragma unroll
        for (int n = 0; n < 4; ++n) {
            int e = n * 16 + r;
            vf[n] = *(const bf16x8*)&sm[16384 + e * 256 + (((c * 4 + g) ^ (r & 7)) << 3)];
        }
        __builtin_amdgcn_s_setprio(1);
#pragma unroll
        for (int m = 0; m < 2; ++m)
#pragma unroll
            for (int n = 0; n < 4; ++n)
                acco[m][n] = mfma16(vf[n], pa[m], acco[m][n]);  // col=s, rows=e
        __builtin_amdgcn_s_setprio(0);
    }

    // write attention output as (b, s, c=h*64+e) bf16, 8B per store
#pragma unroll
    for (int m = 0; m < 2; ++m) {
        const size_t rowb = ((size_t)(b * S_ + sw + m * 16 + r)) * C_ + h * 64;
#pragma unroll
        for (int n = 0; n < 4; ++n) {
            u32 w0 = cvtpk(acco[m][n][0], acco[m][n][1]);
            u32 w1 = cvtpk(acco[m][n][2], acco[m][n][3]);
            *(uint2*)&ao[rowb + n * 16 + g * 4] = make_uint2(w0, w1);
        }
    }
}

// ---------------------------------------------------------------- launch
extern "C" void kernel_launch(void* const* d_in, const int* in_sizes, int n_in,
                              void* d_out, int out_size, void* d_ws, size_t ws_size,
                              hipStream_t stream)
{
    (void)in_sizes; (void)n_in; (void)out_size; (void)ws_size;
    const float* x    = (const float*)d_in[0];
    const float* ctx  = (const float*)d_in[1];
    const float* gn_w = (const float*)d_in[2];
    const float* gn_b = (const float*)d_in[3];
    const float* ln_w = (const float*)d_in[4];
    const float* ln_b = (const float*)d_in[5];
    const float* q_w  = (const float*)d_in[6];
    const float* q_b  = (const float*)d_in[7];
    const float* k_w  = (const float*)d_in[8];
    const float* k_b  = (const float*)d_in[9];
    const float* v_w  = (const float*)d_in[10];
    const float* v_b  = (const float*)d_in[11];
    const float* p_w  = (const float*)d_in[12];
    const float* p_b  = (const float*)d_in[13];
    float* out = (float*)d_out;

    char* ws = (char*)d_ws;
    constexpr size_t WS_WQ   = 0;
    constexpr size_t WS_WK   = WS_WQ + (size_t)512 * 512 * 2;
    constexpr size_t WS_WV   = WS_WK + (size_t)512 * 768 * 2;
    constexpr size_t WS_WP   = WS_WV + (size_t)512 * 768 * 2;
    constexpr size_t WS_PART = WS_WP + (size_t)512 * 512 * 2;
    constexpr size_t WS_CA   = WS_PART + (size_t)16 * 64 * 2 * 4;
    constexpr size_t WS_CB   = WS_CA + 4096;
    constexpr size_t WS_CTXN = WS_CB + 4096;
    constexpr size_t WS_K    = WS_CTXN + (size_t)512 * 768 * 2;
    constexpr size_t WS_V    = WS_K + (size_t)2 * 8 * 256 * 64 * 2;
    constexpr size_t WS_Q    = WS_V + (size_t)2 * 8 * 256 * 64 * 2;
    constexpr size_t WS_H    = WS_Q + (size_t)2 * 32768 * 512 * 2;

    u16* wq = (u16*)(ws + WS_WQ);
    u16* wk = (u16*)(ws + WS_WK);
    u16* wv = (u16*)(ws + WS_WV);
    u16* wp = (u16*)(ws + WS_WP);
    float* part  = (float*)(ws + WS_PART);
    float* coefA = (float*)(ws + WS_CA);
    float* coefB = (float*)(ws + WS_CB);
    u16* ctxn = (u16*)(ws + WS_CTXN);
    u16* kt   = (u16*)(ws + WS_K);
    u16* vt   = (u16*)(ws + WS_V);
    u16* qt   = (u16*)(ws + WS_Q);
    u16* ao   = (u16*)(ws + WS_H);  // attention output buffer

    const size_t bsc = (size_t)S_ * C_;  // per-batch (s,c)/(c,s) stride

    gn_partial<<<dim3(64, 16), 256, 0, stream>>>(x, part);
    prep_small<<<dim3(512, 5), 256, 0, stream>>>(q_w, k_w, v_w, p_w,
                                                 wq, wk, wv, wp,
                                                 ctx, ln_w, ln_b, ctxn);
    gn_final_coef<<<16, 64, 0, stream>>>(part, gn_w, gn_b, coefA, coefB);
    // Q = GN(x) . Wq^T fused (scale folded), out (b,s,o) bf16. SWAP grid:
    // consecutive ids share the x s-tile -> same XCD after swizzle.
    gemm_nt<4, true><<<dim3(4, 256, 2), 256, 0, stream>>>(
        nullptr, wq, q_b, qt, x, 512, 512, 0, 0, bsc, 0.125f,
        nullptr, coefA, coefB);
    // K,V = ctxn . W^T in one launch (z selects)
    gemm_nt<3, false><<<dim3(4, 4, 2), 256, 0, stream>>>(
        ctxn, wk, k_b, kt, nullptr, 768, 512, 0, 0, 0, 1.0f,
        wv, v_b, vt);
    attn_kernel<<<dim3(256, 16), 256, 0, stream>>>(qt, kt, vt, ao);
    // out = Wp . ao^T + bias + x (fp32, (b,c,s)). Consecutive ids share the
    // ao n-tile -> same XCD after swizzle.
    gemm_nt<2, false><<<dim3(4, 256, 2), 256, 0, stream>>>(
        wp, ao, p_b, out, x, 512, S_, 0, bsc, bsc, 1.0f,
        nullptr, nullptr, nullptr);
}